// Round 15
// baseline (612.732 us; speedup 1.0000x reference)
//
#include <hip/hip_runtime.h>
#include <hip/hip_bf16.h>
#include <cmath>

#define N_NODES 50000
#define IN_F 64
#define L 128
#define STEPS 3
#define T_TYPES 4
#define E_EDGES 800000
#define NB4 (N_NODES * 4)
#define ESRC_CAP 1400000   // 800k real + <=3 pad per 200k segments

typedef __attribute__((ext_vector_type(8))) __bf16 bf16x8_t;
typedef __attribute__((ext_vector_type(4))) float f32x4;

__device__ inline float bf2f(ushort u) {
  union { uint i; float f; } v; v.i = ((uint)u) << 16; return v.f;
}
__device__ inline float asf(uint u) {
  union { uint i; float f; } v; v.i = u; return v.f;
}
__device__ inline ushort f2bf(float f) {
  union { float f; uint u; } v; v.f = f;
  uint u = v.u;
  u += 0x7fffu + ((u >> 16) & 1u);  // RNE
  return (ushort)(u >> 16);
}

// ---------------- fp32 tiled matmul for x0 (K=64), writes bf16 ----------------
#define BN 64
#define BO 64
#define BK 16
__global__ __launch_bounds__(256) void matmul_x0(
    const float* __restrict__ A, const float* __restrict__ W,
    const float* __restrict__ bias, ushort* __restrict__ Cb,
    int N, int K, int OUT)
{
  __shared__ float As[BN][BK + 1];
  __shared__ float Ws[BO][BK + 1];
  const int tid = threadIdx.x;
  const int n_base = blockIdx.x * BN;
  const int o_base = blockIdx.y * BO;
  const int tx = tid & 15, ty = tid >> 4;
  const int n0 = ty * 4, o0 = tx * 4;
  const int lr = tid >> 2, lc = (tid & 3) * 4;
  float acc[4][4] = {{0.f, 0.f, 0.f, 0.f}};
  for (int kc = 0; kc < K; kc += BK) {
    int gn = n_base + lr;
    float4 av = make_float4(0.f, 0.f, 0.f, 0.f);
    if (gn < N) av = *(const float4*)(A + (size_t)gn * K + kc + lc);
    As[lr][lc + 0] = av.x; As[lr][lc + 1] = av.y;
    As[lr][lc + 2] = av.z; As[lr][lc + 3] = av.w;
    float4 wv = *(const float4*)(W + (size_t)(o_base + lr) * K + kc + lc);
    Ws[lr][lc + 0] = wv.x; Ws[lr][lc + 1] = wv.y;
    Ws[lr][lc + 2] = wv.z; Ws[lr][lc + 3] = wv.w;
    __syncthreads();
#pragma unroll
    for (int kk = 0; kk < BK; ++kk) {
      float a[4], w[4];
#pragma unroll
      for (int i = 0; i < 4; ++i) a[i] = As[n0 + i][kk];
#pragma unroll
      for (int j = 0; j < 4; ++j) w[j] = Ws[o0 + j][kk];
#pragma unroll
      for (int i = 0; i < 4; ++i)
#pragma unroll
        for (int j = 0; j < 4; ++j) acc[i][j] += a[i] * w[j];
    }
    __syncthreads();
  }
#pragma unroll
  for (int i = 0; i < 4; ++i) {
    int gn = n_base + n0 + i;
    if (gn >= N) continue;
    int o = o_base + o0;
    float v0 = fmaxf(acc[i][0] + bias[o + 0], 0.f);
    float v1 = fmaxf(acc[i][1] + bias[o + 1], 0.f);
    float v2 = fmaxf(acc[i][2] + bias[o + 2], 0.f);
    float v3 = fmaxf(acc[i][3] + bias[o + 3], 0.f);
    uint2 pk;
    pk.x = (uint)f2bf(v0) | ((uint)f2bf(v1) << 16);
    pk.y = (uint)f2bf(v2) | ((uint)f2bf(v3) << 16);
    *(uint2*)(Cb + (size_t)gn * OUT + o) = pk;
  }
}

// ---------------- MFMA GEMM (K=128): KIND 0: bf16+bias (gh). KIND 4: heads mu/lv f32 ----------------
template<int OUT, int KIND>
__global__ __launch_bounds__(256) void gemm_mfma(
    const ushort* __restrict__ A, const ushort* __restrict__ W,
    const float* __restrict__ bias, float* __restrict__ Cf,
    ushort* __restrict__ Cb, const float* __restrict__ bias2,
    float* __restrict__ Cf2, int N)
{
  constexpr int K = 128;
  constexpr int NOT = OUT / 16;
  const int lane = threadIdx.x & 63;
  const int wave = threadIdx.x >> 6;
  const int r = lane & 15;
  const int kg = lane >> 4;
  const int row0 = (blockIdx.x * 8 + wave * 2) * 16;
  if (row0 >= N) return;

  int arow0 = row0 + r;          if (arow0 >= N) arow0 = N - 1;
  int arow1 = row0 + 16 + r;     if (arow1 >= N) arow1 = N - 1;
  const ushort* ap0 = A + (size_t)arow0 * K + kg * 8;
  const ushort* ap1 = A + (size_t)arow1 * K + kg * 8;
  const ushort* wp = W + (size_t)r * K + kg * 8;

  bf16x8_t af[2][4];
#pragma unroll
  for (int kt = 0; kt < 4; ++kt) {
    af[0][kt] = *(const bf16x8_t*)(ap0 + kt * 32);
    af[1][kt] = *(const bf16x8_t*)(ap1 + kt * 32);
  }
#pragma unroll
  for (int otp = 0; otp < NOT / 2; ++otp) {
    bf16x8_t w0[4], w1[4];
#pragma unroll
    for (int kt = 0; kt < 4; ++kt) {
      w0[kt] = *(const bf16x8_t*)(wp + (size_t)(2 * otp) * 16 * K + kt * 32);
      w1[kt] = *(const bf16x8_t*)(wp + (size_t)(2 * otp + 1) * 16 * K + kt * 32);
    }
    f32x4 acc[2][2] = {{{0.f,0.f,0.f,0.f},{0.f,0.f,0.f,0.f}},
                       {{0.f,0.f,0.f,0.f},{0.f,0.f,0.f,0.f}}};
#pragma unroll
    for (int kt = 0; kt < 4; ++kt) {
#pragma unroll
      for (int rt = 0; rt < 2; ++rt) {
        acc[rt][0] = __builtin_amdgcn_mfma_f32_16x16x32_bf16(af[rt][kt], w0[kt], acc[rt][0], 0, 0, 0);
        acc[rt][1] = __builtin_amdgcn_mfma_f32_16x16x32_bf16(af[rt][kt], w1[kt], acc[rt][1], 0, 0, 0);
      }
    }
#pragma unroll
    for (int rt = 0; rt < 2; ++rt) {
#pragma unroll
      for (int oi = 0; oi < 2; ++oi) {
        int o = (2 * otp + oi) * 16 + r;
#pragma unroll
        for (int reg = 0; reg < 4; ++reg) {
          int n = row0 + rt * 16 + kg * 4 + reg;
          if (n >= N) continue;
          float v = acc[rt][oi][reg];
          if constexpr (KIND == 0) {
            Cb[(size_t)n * OUT + o] = f2bf(v + bias[o]);
          } else {
            if (o < 128) Cf[(size_t)n * 128 + o] = v + bias[o];
            else Cf2[(size_t)n * 128 + (o - 128)] = v + bias2[o - 128];
          }
        }
      }
    }
  }
}

// ---------------- fused step: gather(flat, 4 edges/instr)->LDS, sgemm->LDS, GRU->m_out ----------
// block = 16 nodes, 4 waves. Segments padded to x4 so every b_t is 4-aligned:
// flat j+=4 loop never straddles a segment; type routing (j<b1/b2/b3) is scalar-uniform.
// Edge indices preloaded (2x64) and distributed via shfl -> row loads are independent.
__global__ __launch_bounds__(256) void step_fused(
    const ushort* __restrict__ m, const int* __restrict__ offs4,
    const int* __restrict__ esrc, const ushort* __restrict__ Wg,
    const ushort* __restrict__ Wih, const float* __restrict__ bias,
    const ushort* __restrict__ ghb, const ushort* __restrict__ x0b,
    ushort* __restrict__ m_out, int N)
{
  __shared__ ushort s_lds[16 * 512];   // 16KB
  __shared__ ushort a_lds[16 * 128];   // 4KB
  const int tid = threadIdx.x;
  const int lane = tid & 63;
  const int wave = tid >> 6;
  const int node0 = blockIdx.x * 16;

  // ---- phase 1: gather; wave handles 4 nodes, flat unroll-4 loop, 4 edges/load-instr ----
  {
    const int grp = lane >> 4;   // lane group = edge slot (and final type owner)
    const int sub = lane & 15;   // 16B slice within row
#pragma unroll
    for (int i = 0; i < 4; ++i) {
      const int row = wave * 4 + i;
      const int node = node0 + row;
      const int b0 = __builtin_amdgcn_readfirstlane(offs4[node * 4 + 0]);
      const int b1 = __builtin_amdgcn_readfirstlane(offs4[node * 4 + 1]);
      const int b2 = __builtin_amdgcn_readfirstlane(offs4[node * 4 + 2]);
      const int b3 = __builtin_amdgcn_readfirstlane(offs4[node * 4 + 3]);
      const int b4 = __builtin_amdgcn_readfirstlane(offs4[node * 4 + 4]);
      // preload up to 128 edge indices (covers ~100% of nodes), shfl-distributed
      int idx = b0 + lane;
      int pre0 = (idx < b4) ? esrc[idx] : (int)N_NODES;
      int pre1 = (idx + 64 < b4) ? esrc[idx + 64] : (int)N_NODES;
      float4 a0lo = {0,0,0,0}, a0hi = {0,0,0,0};
      float4 a1lo = {0,0,0,0}, a1hi = {0,0,0,0};
      float4 a2lo = {0,0,0,0}, a2hi = {0,0,0,0};
      float4 a3lo = {0,0,0,0}, a3hi = {0,0,0,0};
#pragma unroll 4
      for (int j = b0; j < b4; j += 4) {
        int rel = j - b0 + grp;
        int src;
        if (rel < 64)       src = __shfl(pre0, rel);
        else if (rel < 128) src = __shfl(pre1, rel - 64);
        else                src = esrc[j + grp];
        uint4 h = *(const uint4*)(m + (size_t)src * 128 + sub * 8);
        float l0 = asf(h.x << 16), h0 = asf(h.x & 0xffff0000u);
        float l1 = asf(h.y << 16), h1 = asf(h.y & 0xffff0000u);
        float l2 = asf(h.z << 16), h2 = asf(h.z & 0xffff0000u);
        float l3 = asf(h.w << 16), h3 = asf(h.w & 0xffff0000u);
        if (j < b1) {        // scalar-uniform: b_t are 4-aligned
          a0lo.x += l0; a0hi.x += h0; a0lo.y += l1; a0hi.y += h1;
          a0lo.z += l2; a0hi.z += h2; a0lo.w += l3; a0hi.w += h3;
        } else if (j < b2) {
          a1lo.x += l0; a1hi.x += h0; a1lo.y += l1; a1hi.y += h1;
          a1lo.z += l2; a1hi.z += h2; a1lo.w += l3; a1hi.w += h3;
        } else if (j < b3) {
          a2lo.x += l0; a2hi.x += h0; a2lo.y += l1; a2hi.y += h1;
          a2lo.z += l2; a2hi.z += h2; a2lo.w += l3; a2hi.w += h3;
        } else {
          a3lo.x += l0; a3hi.x += h0; a3lo.y += l1; a3hi.y += h1;
          a3lo.z += l2; a3hi.z += h2; a3lo.w += l3; a3hi.w += h3;
        }
      }

#define RED16(v) { v.x += __shfl_xor(v.x, 16); v.y += __shfl_xor(v.y, 16);    \
                   v.z += __shfl_xor(v.z, 16); v.w += __shfl_xor(v.w, 16); }
#define RED32(v) { v.x += __shfl_xor(v.x, 32); v.y += __shfl_xor(v.y, 32);    \
                   v.z += __shfl_xor(v.z, 32); v.w += __shfl_xor(v.w, 32); }
      RED16(a0lo) RED16(a0hi) RED16(a1lo) RED16(a1hi)
      RED16(a2lo) RED16(a2hi) RED16(a3lo) RED16(a3hi)
      const bool odd = (grp & 1) != 0;
      float4 pLo = odd ? a1lo : a0lo;
      float4 pHi = odd ? a1hi : a0hi;
      float4 qLo = odd ? a3lo : a2lo;
      float4 qHi = odd ? a3hi : a2hi;
      RED32(pLo) RED32(pHi) RED32(qLo) RED32(qHi)
#undef RED16
#undef RED32
      float4 wLo = (grp & 2) ? qLo : pLo;   // grp0:T0 grp1:T1 grp2:T2 grp3:T3
      float4 wHi = (grp & 2) ? qHi : pHi;
      uint4 wpk;
      wpk.x = (uint)f2bf(wLo.x) | ((uint)f2bf(wHi.x) << 16);
      wpk.y = (uint)f2bf(wLo.y) | ((uint)f2bf(wHi.y) << 16);
      wpk.z = (uint)f2bf(wLo.z) | ((uint)f2bf(wHi.z) << 16);
      wpk.w = (uint)f2bf(wLo.w) | ((uint)f2bf(wHi.w) << 16);
      char* srow = (char*)s_lds + row * 1024;
      const int swz = (row & 7) << 4;
      *(uint4*)(srow + ((grp * 256 + sub * 16) ^ swz)) = wpk;
    }
  }
  __syncthreads();

  const int r = lane & 15;
  const int kg = lane >> 4;
  const int rswz = (r & 7) << 4;

  // ---- phase 2: agg = S @ Wg^T (K=512); wave owns out cols [wave*32, wave*32+32) ----
  {
    const ushort* wp = Wg + (size_t)(wave * 32 + r) * 512 + kg * 8;
    f32x4 acc0 = {0.f,0.f,0.f,0.f}, acc1 = {0.f,0.f,0.f,0.f};
#pragma unroll
    for (int kt = 0; kt < 16; ++kt) {
      bf16x8_t w0 = *(const bf16x8_t*)(wp + kt * 32);
      bf16x8_t w1 = *(const bf16x8_t*)(wp + (size_t)16 * 512 + kt * 32);
      bf16x8_t af = *(const bf16x8_t*)((const char*)s_lds +
                      ((r * 1024 + kg * 16 + kt * 64) ^ rswz));
      acc0 = __builtin_amdgcn_mfma_f32_16x16x32_bf16(af, w0, acc0, 0, 0, 0);
      acc1 = __builtin_amdgcn_mfma_f32_16x16x32_bf16(af, w1, acc1, 0, 0, 0);
    }
#pragma unroll
    for (int reg = 0; reg < 4; ++reg) {
      int row = kg * 4 + reg;
      int sw = (row & 7) << 4;
      *(ushort*)((char*)a_lds + ((row * 256 + (wave * 32 + r) * 2) ^ sw)) = f2bf(acc0[reg]);
      *(ushort*)((char*)a_lds + ((row * 256 + (wave * 32 + 16 + r) * 2) ^ sw)) = f2bf(acc1[reg]);
    }
  }
  __syncthreads();

  // ---- phase 3: gi = agg @ w_ih^T (K=128) + GRU epilogue; wave owns jg={wave,wave+4} ----
  bf16x8_t af2[4];
#pragma unroll
  for (int kt = 0; kt < 4; ++kt)
    af2[kt] = *(const bf16x8_t*)((const char*)a_lds +
                ((r * 256 + kg * 16 + kt * 64) ^ rswz));

#pragma unroll
  for (int jl = 0; jl < 2; ++jl) {
    const int jg = wave + jl * 4;
    const ushort* wr = Wih + ((size_t)(0 * 128 + jg * 16 + r)) * 128 + kg * 8;
    const ushort* wz = Wih + ((size_t)(1 * 128 + jg * 16 + r)) * 128 + kg * 8;
    const ushort* wn = Wih + ((size_t)(2 * 128 + jg * 16 + r)) * 128 + kg * 8;
    f32x4 ar = {0.f,0.f,0.f,0.f}, az = {0.f,0.f,0.f,0.f}, an = {0.f,0.f,0.f,0.f};
#pragma unroll
    for (int kt = 0; kt < 4; ++kt) {
      bf16x8_t vr = *(const bf16x8_t*)(wr + kt * 32);
      bf16x8_t vz = *(const bf16x8_t*)(wz + kt * 32);
      bf16x8_t vn = *(const bf16x8_t*)(wn + kt * 32);
      ar = __builtin_amdgcn_mfma_f32_16x16x32_bf16(af2[kt], vr, ar, 0, 0, 0);
      az = __builtin_amdgcn_mfma_f32_16x16x32_bf16(af2[kt], vz, az, 0, 0, 0);
      an = __builtin_amdgcn_mfma_f32_16x16x32_bf16(af2[kt], vn, an, 0, 0, 0);
    }
    const int j = jg * 16 + r;
    const float br = bias[j], bz = bias[128 + j], bn = bias[256 + j];
#pragma unroll
    for (int reg = 0; reg < 4; ++reg) {
      int n = node0 + kg * 4 + reg;
      if (n >= N) continue;
      const ushort* ghp = ghb + (size_t)n * 384;
      float gir = ar[reg] + br + bf2f(ghp[j]);
      float giz = az[reg] + bz + bf2f(ghp[128 + j]);
      float ghn = bf2f(ghp[256 + j]);
      float rr = 1.f / (1.f + expf(-gir));
      float zz = 1.f / (1.f + expf(-giz));
      float nn = tanhf(an[reg] + bn + rr * ghn);
      float x0v = bf2f(x0b[(size_t)n * 128 + j]);
      float h = (1.f - zz) * nn + zz * x0v;
      m_out[(size_t)n * 128 + j] = f2bf(fmaxf(h, 0.f));
    }
  }
}

// ---------------- weight conversion f32 -> bf16 (packed segments) ----------------
// Wg[s][c][t*128+j] = 2 * gnn_w[s][t][c][j]
#define WOFF_WHH 0
#define WOFF_WIH 49152
#define WOFF_WG 98304
#define WOFF_HEADS 294912
#define WTOT 327680

__global__ __launch_bounds__(256) void convert_weights(
    const float* __restrict__ w_hh, const float* __restrict__ w_ih,
    const float* __restrict__ gnn_w, const float* __restrict__ mu_w,
    const float* __restrict__ lv_w, ushort* __restrict__ wsb)
{
  int i = blockIdx.x * 256 + threadIdx.x;
  if (i >= WTOT) return;
  float v;
  if (i < WOFF_WIH) v = w_hh[i];
  else if (i < WOFF_WG) v = w_ih[i - WOFF_WIH];
  else if (i < WOFF_HEADS) {
    int k = i - WOFF_WG;
    int s = k >> 16;
    int rr = k & 65535;
    int c = rr >> 9;
    int col = rr & 511;
    int t = col >> 7;
    int j = col & 127;
    v = 2.f * gnn_w[(((size_t)s * 4 + t) * 128 + c) * 128 + j];
  } else {
    int k = i - WOFF_HEADS;
    v = (k < 16384) ? mu_w[k] : lv_w[k - 16384];
  }
  wsb[i] = f2bf(v);
}

// ---------------- CSR build keyed by (dst*4 + type), segments padded to x4 ----------------
__global__ __launch_bounds__(256) void hist_key(
    const int* __restrict__ ei, const float* __restrict__ ea,
    int* __restrict__ counts, int* __restrict__ ekey)
{
  int e = blockIdx.x * 256 + threadIdx.x;
  if (e >= E_EDGES) return;
  const float* a = ea + (size_t)e * T_TYPES;
  float bv = a[0]; int bi = 0;
#pragma unroll
  for (int t = 1; t < T_TYPES; ++t) {
    float v = a[t];
    if (v > bv) { bv = v; bi = t; }
  }
  int key = ei[E_EDGES + e] * 4 + bi;
  ekey[e] = key;
  atomicAdd(&counts[key], 1);
}

__global__ __launch_bounds__(1024) void scan_block(
    const int* __restrict__ counts, int* __restrict__ excl,
    int* __restrict__ bsum, int n)
{
  __shared__ int ls[1024];
  const int tid = threadIdx.x;
  const int i = blockIdx.x * 1024 + tid;
  int v = (i < n) ? ((counts[i] + 3) & ~3) : 0;   // pad each segment to x4
  ls[tid] = v;
  __syncthreads();
  for (int off = 1; off < 1024; off <<= 1) {
    int t = (tid >= off) ? ls[tid - off] : 0;
    __syncthreads();
    ls[tid] += t;
    __syncthreads();
  }
  if (i < n) excl[i] = ls[tid] - v;
  if (tid == 1023) bsum[blockIdx.x] = ls[1023];
}

// also writes the padded grand total to total_out[0] (= offs4[NB4])
__global__ __launch_bounds__(256) void scan_bsums(
    const int* __restrict__ bsum, int* __restrict__ boff, int nb,
    int* __restrict__ total_out)
{
  __shared__ int ls[256];
  const int tid = threadIdx.x;
  int v = (tid < nb) ? bsum[tid] : 0;
  ls[tid] = v;
  __syncthreads();
  for (int off = 1; off < 256; off <<= 1) {
    int t = (tid >= off) ? ls[tid - off] : 0;
    __syncthreads();
    ls[tid] += t;
    __syncthreads();
  }
  if (tid < nb) boff[tid] = ls[tid] - v;
  if (tid == nb - 1) total_out[0] = ls[tid];   // inclusive total = padded edge count
}

__global__ __launch_bounds__(1024) void scan_final(
    const int* __restrict__ excl, const int* __restrict__ boff,
    int* __restrict__ offsets, int* __restrict__ cursor, int n)
{
  int i = blockIdx.x * 1024 + threadIdx.x;
  if (i >= n) return;
  int o = excl[i] + boff[blockIdx.x];
  offsets[i] = o;
  cursor[i] = o;
}

__global__ __launch_bounds__(256) void fill_dummy(
    int* __restrict__ esrc)
{
  int i = blockIdx.x * 256 + threadIdx.x;
  if (i < ESRC_CAP) esrc[i] = N_NODES;  // zero row
}

__global__ __launch_bounds__(256) void fill_csr(
    const int* __restrict__ ei, const int* __restrict__ ekey,
    int* __restrict__ cursor, int* __restrict__ esrc)
{
  int e = blockIdx.x * 256 + threadIdx.x;
  if (e >= E_EDGES) return;
  int pos = atomicAdd(&cursor[ekey[e]], 1);
  esrc[pos] = ei[e];
}

extern "C" void kernel_launch(void* const* d_in, const int* in_sizes, int n_in,
                              void* d_out, int out_size, void* d_ws, size_t ws_size,
                              hipStream_t stream) {
  const float* x     = (const float*)d_in[0];
  const int*   ei    = (const int*)d_in[1];
  const float* eattr = (const float*)d_in[2];
  const float* lin_w = (const float*)d_in[3];
  const float* lin_b = (const float*)d_in[4];
  const float* gnn_w = (const float*)d_in[5];
  const float* w_ih  = (const float*)d_in[6];
  const float* w_hh  = (const float*)d_in[7];
  const float* b_ih  = (const float*)d_in[8];
  const float* b_hh  = (const float*)d_in[9];
  const float* mu_w  = (const float*)d_in[10];
  const float* mu_b  = (const float*)d_in[11];
  const float* lv_w  = (const float*)d_in[12];
  const float* lv_b  = (const float*)d_in[13];

  char* ws = (char*)d_ws;
  size_t off = 0;
  ushort* x0b = (ushort*)(ws + off); off += (size_t)(N_NODES + 1) * L * 2;  // +zero row
  ushort* ghb = (ushort*)(ws + off); off += (size_t)N_NODES * 3 * L * 2;
  ushort* m_a = (ushort*)(ws + off); off += (size_t)(N_NODES + 1) * L * 2;
  ushort* m_b = (ushort*)(ws + off); off += (size_t)(N_NODES + 1) * L * 2;
  ushort* wsb = (ushort*)(ws + off); off += (size_t)WTOT * 2;
  int* counts  = (int*)(ws + off); off += (NB4 + 1024) * 4;
  int* excl    = (int*)(ws + off); off += (NB4 + 1024) * 4;
  int* offs4   = (int*)(ws + off); off += (NB4 + 1024) * 4;
  int* cursor4 = (int*)(ws + off); off += (NB4 + 1024) * 4;
  int* bsum    = (int*)(ws + off); off += 256 * 4;
  int* boff    = (int*)(ws + off); off += 256 * 4;
  int* ekey    = (int*)(ws + off); off += (size_t)E_EDGES * 4;
  int* esrc    = (int*)(ws + off); off += (size_t)ESRC_CAP * 4;

  dim3 blk(256);
  const int GEMM_GRID = (N_NODES + 127) / 128;
  const int STEP_GRID = (N_NODES + 15) / 16;     // 3125
  const int NSB = (NB4 + 1023) / 1024;           // 196

  convert_weights<<<(WTOT + 255) / 256, blk, 0, stream>>>(
      w_hh, w_ih, gnn_w, mu_w, lv_w, wsb);

  // zero rows for dummy edges
  hipMemsetAsync(x0b + (size_t)N_NODES * L, 0, L * 2, stream);
  hipMemsetAsync(m_a + (size_t)N_NODES * L, 0, L * 2, stream);
  hipMemsetAsync(m_b + (size_t)N_NODES * L, 0, L * 2, stream);

  // CSR keyed by (dst*4+type), padded segments, constant across steps
  hipMemsetAsync(counts, 0, NB4 * sizeof(int), stream);
  hist_key<<<(E_EDGES + 255) / 256, blk, 0, stream>>>(ei, eattr, counts, ekey);
  scan_block<<<NSB, 1024, 0, stream>>>(counts, excl, bsum, NB4);
  scan_bsums<<<1, 256, 0, stream>>>(bsum, boff, NSB, offs4 + NB4);  // true padded total
  scan_final<<<NSB, 1024, 0, stream>>>(excl, boff, offs4, cursor4, NB4);
  fill_dummy<<<(ESRC_CAP + 255) / 256, blk, 0, stream>>>(esrc);
  fill_csr<<<(E_EDGES + 255) / 256, blk, 0, stream>>>(ei, ekey, cursor4, esrc);

  // x0 = relu(x @ lin_w^T + lin_b) -> bf16
  dim3 g_x0((N_NODES + BN - 1) / BN, L / BO);
  matmul_x0<<<g_x0, blk, 0, stream>>>(x, lin_w, lin_b, x0b, N_NODES, IN_F, L);

  // gh = x0 @ w_hh^T + b_hh -> bf16
  gemm_mfma<384, 0><<<GEMM_GRID, blk, 0, stream>>>(
      x0b, wsb + WOFF_WHH, b_hh, nullptr, ghb, nullptr, nullptr, N_NODES);

  // fused per-step kernels with m double-buffering
  const ushort* mcur = x0b;
  ushort* mdst = m_a;
  for (int s = 0; s < STEPS; ++s) {
    step_fused<<<STEP_GRID, blk, 0, stream>>>(
        mcur, offs4, esrc, wsb + WOFF_WG + (size_t)s * 65536,
        wsb + WOFF_WIH, b_ih, ghb, x0b, mdst, N_NODES);
    mcur = mdst;
    mdst = (mdst == m_a) ? m_b : m_a;
  }

  float* mu = (float*)d_out;
  float* lv = (float*)d_out + (size_t)N_NODES * L;
  gemm_mfma<256, 4><<<GEMM_GRID, blk, 0, stream>>>(
      mcur, wsb + WOFF_HEADS, mu_b, mu, nullptr, lv_b, lv, N_NODES);
}

// Round 16
// 546.541 us; speedup vs baseline: 1.1211x; 1.1211x over previous
//
#include <hip/hip_runtime.h>
#include <hip/hip_bf16.h>
#include <cmath>

#define N_NODES 50000
#define IN_F 64
#define L 128
#define STEPS 3
#define T_TYPES 4
#define E_EDGES 800000
#define NB4 (N_NODES * 4)

typedef __attribute__((ext_vector_type(8))) __bf16 bf16x8_t;
typedef __attribute__((ext_vector_type(4))) float f32x4;

__device__ inline float bf2f(ushort u) {
  union { uint i; float f; } v; v.i = ((uint)u) << 16; return v.f;
}
__device__ inline ushort f2bf(float f) {
  union { float f; uint u; } v; v.f = f;
  uint u = v.u;
  u += 0x7fffu + ((u >> 16) & 1u);  // RNE
  return (ushort)(u >> 16);
}

// ---------------- fp32 tiled matmul for x0 (K=64), writes bf16 ----------------
#define BN 64
#define BO 64
#define BK 16
__global__ __launch_bounds__(256) void matmul_x0(
    const float* __restrict__ A, const float* __restrict__ W,
    const float* __restrict__ bias, ushort* __restrict__ Cb,
    int N, int K, int OUT)
{
  __shared__ float As[BN][BK + 1];
  __shared__ float Ws[BO][BK + 1];
  const int tid = threadIdx.x;
  const int n_base = blockIdx.x * BN;
  const int o_base = blockIdx.y * BO;
  const int tx = tid & 15, ty = tid >> 4;
  const int n0 = ty * 4, o0 = tx * 4;
  const int lr = tid >> 2, lc = (tid & 3) * 4;
  float acc[4][4] = {{0.f, 0.f, 0.f, 0.f}};
  for (int kc = 0; kc < K; kc += BK) {
    int gn = n_base + lr;
    float4 av = make_float4(0.f, 0.f, 0.f, 0.f);
    if (gn < N) av = *(const float4*)(A + (size_t)gn * K + kc + lc);
    As[lr][lc + 0] = av.x; As[lr][lc + 1] = av.y;
    As[lr][lc + 2] = av.z; As[lr][lc + 3] = av.w;
    float4 wv = *(const float4*)(W + (size_t)(o_base + lr) * K + kc + lc);
    Ws[lr][lc + 0] = wv.x; Ws[lr][lc + 1] = wv.y;
    Ws[lr][lc + 2] = wv.z; Ws[lr][lc + 3] = wv.w;
    __syncthreads();
#pragma unroll
    for (int kk = 0; kk < BK; ++kk) {
      float a[4], w[4];
#pragma unroll
      for (int i = 0; i < 4; ++i) a[i] = As[n0 + i][kk];
#pragma unroll
      for (int j = 0; j < 4; ++j) w[j] = Ws[o0 + j][kk];
#pragma unroll
      for (int i = 0; i < 4; ++i)
#pragma unroll
        for (int j = 0; j < 4; ++j) acc[i][j] += a[i] * w[j];
    }
    __syncthreads();
  }
#pragma unroll
  for (int i = 0; i < 4; ++i) {
    int gn = n_base + n0 + i;
    if (gn >= N) continue;
    int o = o_base + o0;
    float v0 = fmaxf(acc[i][0] + bias[o + 0], 0.f);
    float v1 = fmaxf(acc[i][1] + bias[o + 1], 0.f);
    float v2 = fmaxf(acc[i][2] + bias[o + 2], 0.f);
    float v3 = fmaxf(acc[i][3] + bias[o + 3], 0.f);
    uint2 pk;
    pk.x = (uint)f2bf(v0) | ((uint)f2bf(v1) << 16);
    pk.y = (uint)f2bf(v2) | ((uint)f2bf(v3) << 16);
    *(uint2*)(Cb + (size_t)gn * OUT + o) = pk;
  }
}

// ---------------- MFMA GEMM (K=128): KIND 0: bf16+bias (gh). KIND 4: heads mu/lv f32 ----------------
template<int OUT, int KIND>
__global__ __launch_bounds__(256) void gemm_mfma(
    const ushort* __restrict__ A, const ushort* __restrict__ W,
    const float* __restrict__ bias, float* __restrict__ Cf,
    ushort* __restrict__ Cb, const float* __restrict__ bias2,
    float* __restrict__ Cf2, int N)
{
  constexpr int K = 128;
  constexpr int NOT = OUT / 16;
  const int lane = threadIdx.x & 63;
  const int wave = threadIdx.x >> 6;
  const int r = lane & 15;
  const int kg = lane >> 4;
  const int row0 = (blockIdx.x * 8 + wave * 2) * 16;
  if (row0 >= N) return;

  int arow0 = row0 + r;          if (arow0 >= N) arow0 = N - 1;
  int arow1 = row0 + 16 + r;     if (arow1 >= N) arow1 = N - 1;
  const ushort* ap0 = A + (size_t)arow0 * K + kg * 8;
  const ushort* ap1 = A + (size_t)arow1 * K + kg * 8;
  const ushort* wp = W + (size_t)r * K + kg * 8;

  bf16x8_t af[2][4];
#pragma unroll
  for (int kt = 0; kt < 4; ++kt) {
    af[0][kt] = *(const bf16x8_t*)(ap0 + kt * 32);
    af[1][kt] = *(const bf16x8_t*)(ap1 + kt * 32);
  }
#pragma unroll
  for (int otp = 0; otp < NOT / 2; ++otp) {
    bf16x8_t w0[4], w1[4];
#pragma unroll
    for (int kt = 0; kt < 4; ++kt) {
      w0[kt] = *(const bf16x8_t*)(wp + (size_t)(2 * otp) * 16 * K + kt * 32);
      w1[kt] = *(const bf16x8_t*)(wp + (size_t)(2 * otp + 1) * 16 * K + kt * 32);
    }
    f32x4 acc[2][2] = {{{0.f,0.f,0.f,0.f},{0.f,0.f,0.f,0.f}},
                       {{0.f,0.f,0.f,0.f},{0.f,0.f,0.f,0.f}}};
#pragma unroll
    for (int kt = 0; kt < 4; ++kt) {
#pragma unroll
      for (int rt = 0; rt < 2; ++rt) {
        acc[rt][0] = __builtin_amdgcn_mfma_f32_16x16x32_bf16(af[rt][kt], w0[kt], acc[rt][0], 0, 0, 0);
        acc[rt][1] = __builtin_amdgcn_mfma_f32_16x16x32_bf16(af[rt][kt], w1[kt], acc[rt][1], 0, 0, 0);
      }
    }
#pragma unroll
    for (int rt = 0; rt < 2; ++rt) {
#pragma unroll
      for (int oi = 0; oi < 2; ++oi) {
        int o = (2 * otp + oi) * 16 + r;
#pragma unroll
        for (int reg = 0; reg < 4; ++reg) {
          int n = row0 + rt * 16 + kg * 4 + reg;
          if (n >= N) continue;
          float v = acc[rt][oi][reg];
          if constexpr (KIND == 0) {
            Cb[(size_t)n * OUT + o] = f2bf(v + bias[o]);
          } else {
            if (o < 128) Cf[(size_t)n * 128 + o] = v + bias[o];
            else Cf2[(size_t)n * 128 + (o - 128)] = v + bias2[o - 128];
          }
        }
      }
    }
  }
}

// ---------------- fused step: gather->LDS, sgemm->LDS, GRU->m_out ----------------
// block = 16 nodes, 4 waves. s_lds[16][512] and a_lds[16][128] XOR-swizzled:
// byte ^= ((row&7)<<4) so column-slice b128 reads hit 8 distinct 16B slots (2-way, free).
// Gather: unroll-8 over the node's WHOLE edge range; type routing via wave-uniform
// branches (j vs b1/b2/b3, all scalar) -> 8 independent row loads in flight.
__global__ __launch_bounds__(256) void step_fused(
    const ushort* __restrict__ m, const int* __restrict__ offs4,
    const int* __restrict__ esrc, const ushort* __restrict__ Wg,
    const ushort* __restrict__ Wih, const float* __restrict__ bias,
    const ushort* __restrict__ ghb, const ushort* __restrict__ x0b,
    ushort* __restrict__ m_out, int N)
{
  __shared__ ushort s_lds[16 * 512];   // 16KB
  __shared__ ushort a_lds[16 * 128];   // 4KB
  const int tid = threadIdx.x;
  const int lane = tid & 63;
  const int wave = tid >> 6;
  const int node0 = blockIdx.x * 16;

  // ---- phase 1: gather; wave handles 4 nodes ----
  {
    const int ch = lane * 2;
#pragma unroll
    for (int i = 0; i < 4; ++i) {
      const int row = wave * 4 + i;
      const int node = node0 + row;
      const int b0 = __builtin_amdgcn_readfirstlane(offs4[node * 4 + 0]);
      const int b1 = __builtin_amdgcn_readfirstlane(offs4[node * 4 + 1]);
      const int b2 = __builtin_amdgcn_readfirstlane(offs4[node * 4 + 2]);
      const int b3 = __builtin_amdgcn_readfirstlane(offs4[node * 4 + 3]);
      const int b4 = __builtin_amdgcn_readfirstlane(offs4[node * 4 + 4]);
      float a0x = 0.f, a0y = 0.f, a1x = 0.f, a1y = 0.f;
      float a2x = 0.f, a2y = 0.f, a3x = 0.f, a3y = 0.f;

#define ACCUM(hv, jj)                                                 \
      { float lo_ = bf2f((ushort)((hv) & 0xffff));                    \
        float hi_ = bf2f((ushort)((hv) >> 16));                       \
        if ((jj) < b1)      { a0x += lo_; a0y += hi_; }               \
        else if ((jj) < b2) { a1x += lo_; a1y += hi_; }               \
        else if ((jj) < b3) { a2x += lo_; a2y += hi_; }               \
        else                { a3x += lo_; a3y += hi_; } }

      int j = b0;
      for (; j + 7 < b4; j += 8) {
        int s0 = esrc[j + 0], s1 = esrc[j + 1], s2 = esrc[j + 2], s3 = esrc[j + 3];
        int s4 = esrc[j + 4], s5 = esrc[j + 5], s6 = esrc[j + 6], s7 = esrc[j + 7];
        uint h0 = *(const uint*)(m + (size_t)s0 * 128 + ch);
        uint h1 = *(const uint*)(m + (size_t)s1 * 128 + ch);
        uint h2 = *(const uint*)(m + (size_t)s2 * 128 + ch);
        uint h3 = *(const uint*)(m + (size_t)s3 * 128 + ch);
        uint h4 = *(const uint*)(m + (size_t)s4 * 128 + ch);
        uint h5 = *(const uint*)(m + (size_t)s5 * 128 + ch);
        uint h6 = *(const uint*)(m + (size_t)s6 * 128 + ch);
        uint h7 = *(const uint*)(m + (size_t)s7 * 128 + ch);
        ACCUM(h0, j + 0) ACCUM(h1, j + 1) ACCUM(h2, j + 2) ACCUM(h3, j + 3)
        ACCUM(h4, j + 4) ACCUM(h5, j + 5) ACCUM(h6, j + 6) ACCUM(h7, j + 7)
      }
      for (; j + 1 < b4; j += 2) {
        int s0 = esrc[j + 0], s1 = esrc[j + 1];
        uint h0 = *(const uint*)(m + (size_t)s0 * 128 + ch);
        uint h1 = *(const uint*)(m + (size_t)s1 * 128 + ch);
        ACCUM(h0, j + 0) ACCUM(h1, j + 1)
      }
      if (j < b4) {
        int s0 = esrc[j];
        uint h0 = *(const uint*)(m + (size_t)s0 * 128 + ch);
        ACCUM(h0, j)
      }
#undef ACCUM

      char* srow = (char*)s_lds + row * 1024;
      const int swz = (row & 7) << 4;
      *(uint*)(srow + ((0 * 256 + lane * 4) ^ swz)) = (uint)f2bf(a0x) | ((uint)f2bf(a0y) << 16);
      *(uint*)(srow + ((1 * 256 + lane * 4) ^ swz)) = (uint)f2bf(a1x) | ((uint)f2bf(a1y) << 16);
      *(uint*)(srow + ((2 * 256 + lane * 4) ^ swz)) = (uint)f2bf(a2x) | ((uint)f2bf(a2y) << 16);
      *(uint*)(srow + ((3 * 256 + lane * 4) ^ swz)) = (uint)f2bf(a3x) | ((uint)f2bf(a3y) << 16);
    }
  }
  __syncthreads();

  const int r = lane & 15;
  const int kg = lane >> 4;
  const int rswz = (r & 7) << 4;

  // ---- phase 2: agg = S @ Wg^T (K=512); wave owns out cols [wave*32, wave*32+32) ----
  {
    const ushort* wp = Wg + (size_t)(wave * 32 + r) * 512 + kg * 8;
    f32x4 acc0 = {0.f,0.f,0.f,0.f}, acc1 = {0.f,0.f,0.f,0.f};
#pragma unroll
    for (int kt = 0; kt < 16; ++kt) {
      bf16x8_t w0 = *(const bf16x8_t*)(wp + kt * 32);
      bf16x8_t w1 = *(const bf16x8_t*)(wp + (size_t)16 * 512 + kt * 32);
      bf16x8_t af = *(const bf16x8_t*)((const char*)s_lds +
                      ((r * 1024 + kg * 16 + kt * 64) ^ rswz));
      acc0 = __builtin_amdgcn_mfma_f32_16x16x32_bf16(af, w0, acc0, 0, 0, 0);
      acc1 = __builtin_amdgcn_mfma_f32_16x16x32_bf16(af, w1, acc1, 0, 0, 0);
    }
#pragma unroll
    for (int reg = 0; reg < 4; ++reg) {
      int row = kg * 4 + reg;
      int sw = (row & 7) << 4;
      *(ushort*)((char*)a_lds + ((row * 256 + (wave * 32 + r) * 2) ^ sw)) = f2bf(acc0[reg]);
      *(ushort*)((char*)a_lds + ((row * 256 + (wave * 32 + 16 + r) * 2) ^ sw)) = f2bf(acc1[reg]);
    }
  }
  __syncthreads();

  // ---- phase 3: gi = agg @ w_ih^T (K=128) + GRU epilogue; wave owns jg={wave,wave+4} ----
  bf16x8_t af2[4];
#pragma unroll
  for (int kt = 0; kt < 4; ++kt)
    af2[kt] = *(const bf16x8_t*)((const char*)a_lds +
                ((r * 256 + kg * 16 + kt * 64) ^ rswz));

#pragma unroll
  for (int jl = 0; jl < 2; ++jl) {
    const int jg = wave + jl * 4;
    const ushort* wr = Wih + ((size_t)(0 * 128 + jg * 16 + r)) * 128 + kg * 8;
    const ushort* wz = Wih + ((size_t)(1 * 128 + jg * 16 + r)) * 128 + kg * 8;
    const ushort* wn = Wih + ((size_t)(2 * 128 + jg * 16 + r)) * 128 + kg * 8;
    f32x4 ar = {0.f,0.f,0.f,0.f}, az = {0.f,0.f,0.f,0.f}, an = {0.f,0.f,0.f,0.f};
#pragma unroll
    for (int kt = 0; kt < 4; ++kt) {
      bf16x8_t vr = *(const bf16x8_t*)(wr + kt * 32);
      bf16x8_t vz = *(const bf16x8_t*)(wz + kt * 32);
      bf16x8_t vn = *(const bf16x8_t*)(wn + kt * 32);
      ar = __builtin_amdgcn_mfma_f32_16x16x32_bf16(af2[kt], vr, ar, 0, 0, 0);
      az = __builtin_amdgcn_mfma_f32_16x16x32_bf16(af2[kt], vz, az, 0, 0, 0);
      an = __builtin_amdgcn_mfma_f32_16x16x32_bf16(af2[kt], vn, an, 0, 0, 0);
    }
    const int j = jg * 16 + r;
    const float br = bias[j], bz = bias[128 + j], bn = bias[256 + j];
#pragma unroll
    for (int reg = 0; reg < 4; ++reg) {
      int n = node0 + kg * 4 + reg;
      if (n >= N) continue;
      const ushort* ghp = ghb + (size_t)n * 384;
      float gir = ar[reg] + br + bf2f(ghp[j]);
      float giz = az[reg] + bz + bf2f(ghp[128 + j]);
      float ghn = bf2f(ghp[256 + j]);
      float rr = 1.f / (1.f + expf(-gir));
      float zz = 1.f / (1.f + expf(-giz));
      float nn = tanhf(an[reg] + bn + rr * ghn);
      float x0v = bf2f(x0b[(size_t)n * 128 + j]);
      float h = (1.f - zz) * nn + zz * x0v;
      m_out[(size_t)n * 128 + j] = f2bf(fmaxf(h, 0.f));
    }
  }
}

// ---------------- weight conversion f32 -> bf16 (packed segments) ----------------
// Wg[s][c][t*128+j] = 2 * gnn_w[s][t][c][j]
#define WOFF_WHH 0
#define WOFF_WIH 49152
#define WOFF_WG 98304
#define WOFF_HEADS 294912
#define WTOT 327680

__global__ __launch_bounds__(256) void convert_weights(
    const float* __restrict__ w_hh, const float* __restrict__ w_ih,
    const float* __restrict__ gnn_w, const float* __restrict__ mu_w,
    const float* __restrict__ lv_w, ushort* __restrict__ wsb)
{
  int i = blockIdx.x * 256 + threadIdx.x;
  if (i >= WTOT) return;
  float v;
  if (i < WOFF_WIH) v = w_hh[i];
  else if (i < WOFF_WG) v = w_ih[i - WOFF_WIH];
  else if (i < WOFF_HEADS) {
    int k = i - WOFF_WG;
    int s = k >> 16;
    int rr = k & 65535;
    int c = rr >> 9;
    int col = rr & 511;
    int t = col >> 7;
    int j = col & 127;
    v = 2.f * gnn_w[(((size_t)s * 4 + t) * 128 + c) * 128 + j];
  } else {
    int k = i - WOFF_HEADS;
    v = (k < 16384) ? mu_w[k] : lv_w[k - 16384];
  }
  wsb[i] = f2bf(v);
}

// ---------------- CSR build keyed by (dst*4 + type) ----------------
__global__ __launch_bounds__(256) void hist_key(
    const int* __restrict__ ei, const float* __restrict__ ea,
    int* __restrict__ counts, int* __restrict__ ekey)
{
  int e = blockIdx.x * 256 + threadIdx.x;
  if (e >= E_EDGES) return;
  const float* a = ea + (size_t)e * T_TYPES;
  float bv = a[0]; int bi = 0;
#pragma unroll
  for (int t = 1; t < T_TYPES; ++t) {
    float v = a[t];
    if (v > bv) { bv = v; bi = t; }
  }
  int key = ei[E_EDGES + e] * 4 + bi;
  ekey[e] = key;
  atomicAdd(&counts[key], 1);
}

__global__ __launch_bounds__(1024) void scan_block(
    const int* __restrict__ counts, int* __restrict__ excl,
    int* __restrict__ bsum, int n)
{
  __shared__ int ls[1024];
  const int tid = threadIdx.x;
  const int i = blockIdx.x * 1024 + tid;
  int v = (i < n) ? counts[i] : 0;
  ls[tid] = v;
  __syncthreads();
  for (int off = 1; off < 1024; off <<= 1) {
    int t = (tid >= off) ? ls[tid - off] : 0;
    __syncthreads();
    ls[tid] += t;
    __syncthreads();
  }
  if (i < n) excl[i] = ls[tid] - v;
  if (tid == 1023) bsum[blockIdx.x] = ls[1023];
}

__global__ __launch_bounds__(256) void scan_bsums(
    const int* __restrict__ bsum, int* __restrict__ boff, int nb)
{
  __shared__ int ls[256];
  const int tid = threadIdx.x;
  int v = (tid < nb) ? bsum[tid] : 0;
  ls[tid] = v;
  __syncthreads();
  for (int off = 1; off < 256; off <<= 1) {
    int t = (tid >= off) ? ls[tid - off] : 0;
    __syncthreads();
    ls[tid] += t;
    __syncthreads();
  }
  if (tid < nb) boff[tid] = ls[tid] - v;
}

__global__ __launch_bounds__(1024) void scan_final(
    const int* __restrict__ excl, const int* __restrict__ boff,
    int* __restrict__ offsets, int* __restrict__ cursor, int n)
{
  int i = blockIdx.x * 1024 + threadIdx.x;
  if (i == 0) { offsets[n] = E_EDGES; }
  if (i >= n) return;
  int o = excl[i] + boff[blockIdx.x];
  offsets[i] = o;
  cursor[i] = o;
}

__global__ __launch_bounds__(256) void fill_csr(
    const int* __restrict__ ei, const int* __restrict__ ekey,
    int* __restrict__ cursor, int* __restrict__ esrc)
{
  int e = blockIdx.x * 256 + threadIdx.x;
  if (e >= E_EDGES) return;
  int pos = atomicAdd(&cursor[ekey[e]], 1);
  esrc[pos] = ei[e];
}

extern "C" void kernel_launch(void* const* d_in, const int* in_sizes, int n_in,
                              void* d_out, int out_size, void* d_ws, size_t ws_size,
                              hipStream_t stream) {
  const float* x     = (const float*)d_in[0];
  const int*   ei    = (const int*)d_in[1];
  const float* eattr = (const float*)d_in[2];
  const float* lin_w = (const float*)d_in[3];
  const float* lin_b = (const float*)d_in[4];
  const float* gnn_w = (const float*)d_in[5];
  const float* w_ih  = (const float*)d_in[6];
  const float* w_hh  = (const float*)d_in[7];
  const float* b_ih  = (const float*)d_in[8];
  const float* b_hh  = (const float*)d_in[9];
  const float* mu_w  = (const float*)d_in[10];
  const float* mu_b  = (const float*)d_in[11];
  const float* lv_w  = (const float*)d_in[12];
  const float* lv_b  = (const float*)d_in[13];

  char* ws = (char*)d_ws;
  size_t off = 0;
  ushort* x0b = (ushort*)(ws + off); off += (size_t)N_NODES * L * 2;        // 12.8MB
  ushort* ghb = (ushort*)(ws + off); off += (size_t)N_NODES * 3 * L * 2;    // 38.4MB
  ushort* m_a = (ushort*)(ws + off); off += (size_t)N_NODES * L * 2;        // 12.8MB
  ushort* m_b = (ushort*)(ws + off); off += (size_t)N_NODES * L * 2;        // 12.8MB
  ushort* wsb = (ushort*)(ws + off); off += (size_t)WTOT * 2;               // 0.66MB
  int* counts  = (int*)(ws + off); off += (NB4 + 1024) * 4;
  int* excl    = (int*)(ws + off); off += (NB4 + 1024) * 4;
  int* offs4   = (int*)(ws + off); off += (NB4 + 1024) * 4;
  int* cursor4 = (int*)(ws + off); off += (NB4 + 1024) * 4;
  int* bsum    = (int*)(ws + off); off += 256 * 4;
  int* boff    = (int*)(ws + off); off += 256 * 4;
  int* ekey    = (int*)(ws + off); off += (size_t)E_EDGES * 4;
  int* esrc    = (int*)(ws + off); off += (size_t)E_EDGES * 4;

  dim3 blk(256);
  const int GEMM_GRID = (N_NODES + 127) / 128;   // 391 (gh, heads)
  const int STEP_GRID = (N_NODES + 15) / 16;     // 3125
  const int NSB = (NB4 + 1023) / 1024;           // 196

  convert_weights<<<(WTOT + 255) / 256, blk, 0, stream>>>(
      w_hh, w_ih, gnn_w, mu_w, lv_w, wsb);

  // CSR keyed by (dst*4+type), constant across steps
  hipMemsetAsync(counts, 0, NB4 * sizeof(int), stream);
  hist_key<<<(E_EDGES + 255) / 256, blk, 0, stream>>>(ei, eattr, counts, ekey);
  scan_block<<<NSB, 1024, 0, stream>>>(counts, excl, bsum, NB4);
  scan_bsums<<<1, 256, 0, stream>>>(bsum, boff, NSB);
  scan_final<<<NSB, 1024, 0, stream>>>(excl, boff, offs4, cursor4, NB4);
  fill_csr<<<(E_EDGES + 255) / 256, blk, 0, stream>>>(ei, ekey, cursor4, esrc);

  // x0 = relu(x @ lin_w^T + lin_b) -> bf16
  dim3 g_x0((N_NODES + BN - 1) / BN, L / BO);
  matmul_x0<<<g_x0, blk, 0, stream>>>(x, lin_w, lin_b, x0b, N_NODES, IN_F, L);

  // gh = x0 @ w_hh^T + b_hh -> bf16
  gemm_mfma<384, 0><<<GEMM_GRID, blk, 0, stream>>>(
      x0b, wsb + WOFF_WHH, b_hh, nullptr, ghb, nullptr, nullptr, N_NODES);

  // fused per-step kernels with m double-buffering
  const ushort* mcur = x0b;
  ushort* mdst = m_a;
  for (int s = 0; s < STEPS; ++s) {
    step_fused<<<STEP_GRID, blk, 0, stream>>>(
        mcur, offs4, esrc, wsb + WOFF_WG + (size_t)s * 65536,
        wsb + WOFF_WIH, b_ih, ghb, x0b, mdst, N_NODES);
    mcur = mdst;
    mdst = (mdst == m_a) ? m_b : m_a;
  }

  float* mu = (float*)d_out;
  float* lv = (float*)d_out + (size_t)N_NODES * L;
  gemm_mfma<256, 4><<<GEMM_GRID, blk, 0, stream>>>(
      mcur, wsb + WOFF_HEADS, mu_b, mu, nullptr, lv_b, lv, N_NODES);
}